// Round 4
// baseline (566.540 us; speedup 1.0000x reference)
//
#include <hip/hip_runtime.h>
#include <hip/hip_bf16.h>

#define N_EXPERTS 8
#define EMB 1024
#define HID 2816
#define NTOK 4096
#define NSLOT (NTOK * 2)
#define TLIST NTOK

typedef float f32x4 __attribute__((ext_vector_type(4)));
typedef short short8 __attribute__((ext_vector_type(8)));

static __device__ __forceinline__ unsigned short f2bf(float v) {
    __hip_bfloat16 b = __float2bfloat16(v);
    return *reinterpret_cast<unsigned short*>(&b);
}
static __device__ __forceinline__ float bf2f(unsigned short u) {
    unsigned int w = ((unsigned int)u) << 16;
    return __builtin_bit_cast(float, w);
}

// async global->LDS, 16B per lane. LDS dest = wave-uniform base + lane*16.
static __device__ __forceinline__ void ldst16(const unsigned short* g, unsigned short* l) {
    __builtin_amdgcn_global_load_lds(
        (const __attribute__((address_space(1))) unsigned int*)g,
        (__attribute__((address_space(3))) unsigned int*)l,
        16, 0, 0);
}

// ---------- weight transpose + fp32->bf16: in [E][R][C] f32 -> out [E][C][R] bf16 ----------
// transpose during LDS *write* (4 scalar ds_writes), so LDS reads and global stores are wide.
__global__ __launch_bounds__(256) void transpose_cvt(const float* __restrict__ in,
                                                     unsigned short* __restrict__ out,
                                                     int R, int C) {
    __shared__ unsigned short tileT[64][68];   // [c][r], stride 68 shorts (8B-aligned rows)
    int e = blockIdx.z;
    int r0 = blockIdx.y * 64, c0 = blockIdx.x * 64;
    const float* src = in + (size_t)e * R * C;
    unsigned short* dst = out + (size_t)e * R * C;
    int tid = threadIdx.x;
#pragma unroll
    for (int i = 0; i < 4; ++i) {
        int lin = i * 256 + tid;
        int r = lin >> 4, c4 = (lin & 15) * 4;
        float4 v = *(const float4*)&src[(size_t)(r0 + r) * C + c0 + c4];
        tileT[c4 + 0][r] = f2bf(v.x);
        tileT[c4 + 1][r] = f2bf(v.y);
        tileT[c4 + 2][r] = f2bf(v.z);
        tileT[c4 + 3][r] = f2bf(v.w);
    }
    __syncthreads();
#pragma unroll
    for (int i = 0; i < 2; ++i) {
        int lin = i * 256 + tid;
        int c = lin >> 3, r8 = (lin & 7) * 8;
        ushort4 lo = *(const ushort4*)&tileT[c][r8];
        ushort4 hi = *(const ushort4*)&tileT[c][r8 + 4];
        unsigned short* d = &dst[(size_t)(c0 + c) * R + r0 + r8];
        *(ushort4*)d = lo;
        *(ushort4*)(d + 4) = hi;
    }
}

// ---------- router: fp32 scores, top-2 softmax -> sel + gates; x -> bf16. NO atomics. ----------
__global__ __launch_bounds__(64) void router_kernel(const float* __restrict__ x,
                                                    const float* __restrict__ wr,
                                                    unsigned short* __restrict__ xbf,
                                                    int* __restrict__ sel,
                                                    float* __restrict__ gates) {
    int t = blockIdx.x, lane = threadIdx.x;
    const float* xr = x + (size_t)t * EMB;
    float acc[N_EXPERTS];
#pragma unroll
    for (int e = 0; e < N_EXPERTS; ++e) acc[e] = 0.f;
#pragma unroll
    for (int it = 0; it < EMB / 256; ++it) {
        int d4 = it * 256 + lane * 4;
        float4 xv = *(const float4*)&xr[d4];
        ushort4 b;
        b.x = f2bf(xv.x); b.y = f2bf(xv.y); b.z = f2bf(xv.z); b.w = f2bf(xv.w);
        *(ushort4*)&xbf[(size_t)t * EMB + d4] = b;
        const float* w0 = wr + (size_t)d4 * N_EXPERTS;
#pragma unroll
        for (int e = 0; e < N_EXPERTS; ++e)
            acc[e] += xv.x * w0[e] + xv.y * w0[8 + e] + xv.z * w0[16 + e] + xv.w * w0[24 + e];
    }
#pragma unroll
    for (int off = 32; off; off >>= 1) {
#pragma unroll
        for (int e = 0; e < N_EXPERTS; ++e) acc[e] += __shfl_xor(acc[e], off, 64);
    }
    if (lane == 0) {
        int b0 = 0; float v0 = acc[0];
#pragma unroll
        for (int e = 1; e < N_EXPERTS; ++e) if (acc[e] > v0) { v0 = acc[e]; b0 = e; }
        int b1 = -1; float v1 = -1e30f;
#pragma unroll
        for (int e = 0; e < N_EXPERTS; ++e) if (e != b0 && acc[e] > v1) { v1 = acc[e]; b1 = e; }
        float g0 = 1.f / (1.f + expf(v1 - v0));
        float g1 = 1.f - g0;
        sel[t] = b0 | (b1 << 8);
        gates[2 * t] = g0;
        gates[2 * t + 1] = g1;
    }
}

// ---------- deterministic list build: one block per expert, ordered ballot compaction ----------
__global__ __launch_bounds__(256) void build_lists(const int* __restrict__ sel,
                                                   int* __restrict__ counts,
                                                   int* __restrict__ lists) {
    int e = blockIdx.x;
    int tid = threadIdx.x, lane = tid & 63, wid = tid >> 6;
    __shared__ int wsum[4];
    __shared__ int running;
    if (tid == 0) running = 0;
    __syncthreads();
    for (int base = 0; base < NTOK; base += 256) {
        int tok = base + tid;
        int s = sel[tok];
        int e0 = s & 0xff, e1 = (s >> 8) & 0xff;
        bool take = (e0 == e) || (e1 == e);
        int slot = (e0 == e) ? 2 * tok : 2 * tok + 1;
        unsigned long long b = __ballot(take);
        int lp = __popcll(b & ((1ull << lane) - 1ull));
        if (lane == 0) wsum[wid] = __popcll(b);
        __syncthreads();
        int off = running;
        for (int w = 0; w < wid; ++w) off += wsum[w];
        if (take) lists[e * TLIST + off + lp] = slot;
        __syncthreads();
        if (tid == 0) running += wsum[0] + wsum[1] + wsum[2] + wsum[3];
        __syncthreads();
    }
    if (tid == 0) counts[e] = running;
}

// ---------- GEMM1: h[slot] = silu(x@w1) * (x@w3), bf16 out ----------
// 128(M) x 128(N per matrix) x 32(K); 4 waves 2x2; 32 MFMA : 12 ds_read per wave-iter
__global__ __launch_bounds__(256, 2) void gemm1_kernel(const unsigned short* __restrict__ xbf,
                                                       const unsigned short* __restrict__ w1T,
                                                       const unsigned short* __restrict__ w3T,
                                                       unsigned short* __restrict__ h,
                                                       const int* __restrict__ counts,
                                                       const int* __restrict__ lists) {
    int e = blockIdx.z;
    int cnt = counts[e];
    int rt = blockIdx.y;
    if (rt * 128 >= cnt) return;
    int n0 = blockIdx.x * 128;

    __shared__ unsigned short As[128 * 32];
    __shared__ unsigned short B1s[128 * 32];
    __shared__ unsigned short B3s[128 * 32];
    __shared__ int slotArr[128];

    int tid = threadIdx.x;
    if (tid < 128) {
        int r = rt * 128 + tid;
        slotArr[tid] = (r < cnt) ? lists[e * TLIST + r] : -1;
    }
    __syncthreads();

    int lane = tid & 63, wid = tid >> 6;
    int seg = lane >> 2, chunk = lane & 3;

    int rA0 = wid * 32 + seg, rA1 = wid * 32 + 16 + seg;
    int s0 = slotArr[rA0], s1 = slotArr[rA1];
    int t0 = s0 >= 0 ? (s0 >> 1) : 0, t1 = s1 >= 0 ? (s1 >> 1) : 0;
    const unsigned short* gA0 = xbf + (size_t)t0 * EMB + chunk * 8;
    const unsigned short* gA1 = xbf + (size_t)t1 * EMB + chunk * 8;
    int rB0 = n0 + wid * 32 + seg, rB1 = rB0 + 16;
    const unsigned short* gB10 = w1T + ((size_t)e * HID + rB0) * EMB + chunk * 8;
    const unsigned short* gB11 = w1T + ((size_t)e * HID + rB1) * EMB + chunk * 8;
    const unsigned short* gB30 = w3T + ((size_t)e * HID + rB0) * EMB + chunk * 8;
    const unsigned short* gB31 = w3T + ((size_t)e * HID + rB1) * EMB + chunk * 8;
    unsigned short* lA0 = &As[wid * 1024];
    unsigned short* lA1 = &As[wid * 1024 + 512];
    unsigned short* lB10 = &B1s[wid * 1024];
    unsigned short* lB11 = &B1s[wid * 1024 + 512];
    unsigned short* lB30 = &B3s[wid * 1024];
    unsigned short* lB31 = &B3s[wid * 1024 + 512];

    int wr = wid >> 1, wc = wid & 1;
    int lrow = lane & 15, quad = lane >> 4;

    f32x4 zero4 = {0.f, 0.f, 0.f, 0.f};
    f32x4 acc1[4][4], acc3[4][4];
#pragma unroll
    for (int mt = 0; mt < 4; ++mt)
#pragma unroll
        for (int nt = 0; nt < 4; ++nt) { acc1[mt][nt] = zero4; acc3[mt][nt] = zero4; }

    const int KT = EMB / 32;
    for (int kt = 0; kt < KT; ++kt) {
        ldst16(gA0, lA0); ldst16(gA1, lA1);
        ldst16(gB10, lB10); ldst16(gB11, lB11);
        ldst16(gB30, lB30); ldst16(gB31, lB31);
        gA0 += 32; gA1 += 32; gB10 += 32; gB11 += 32; gB30 += 32; gB31 += 32;
        __builtin_amdgcn_s_waitcnt(0);
        __syncthreads();
        short8 af[4], b1f[4], b3f[4];
#pragma unroll
        for (int mt = 0; mt < 4; ++mt)
            af[mt] = *(const short8*)&As[(wr * 64 + mt * 16 + lrow) * 32 + quad * 8];
#pragma unroll
        for (int nt = 0; nt < 4; ++nt) {
            b1f[nt] = *(const short8*)&B1s[(wc * 64 + nt * 16 + lrow) * 32 + quad * 8];
            b3f[nt] = *(const short8*)&B3s[(wc * 64 + nt * 16 + lrow) * 32 + quad * 8];
        }
#pragma unroll
        for (int mt = 0; mt < 4; ++mt)
#pragma unroll
            for (int nt = 0; nt < 4; ++nt) {
                acc1[mt][nt] = __builtin_amdgcn_mfma_f32_16x16x32_bf16(af[mt], b1f[nt], acc1[mt][nt], 0, 0, 0);
                acc3[mt][nt] = __builtin_amdgcn_mfma_f32_16x16x32_bf16(af[mt], b3f[nt], acc3[mt][nt], 0, 0, 0);
            }
        __syncthreads();
    }

#pragma unroll
    for (int mt = 0; mt < 4; ++mt) {
#pragma unroll
        for (int i = 0; i < 4; ++i) {
            int r = wr * 64 + mt * 16 + quad * 4 + i;
            int slot = slotArr[r];
            if (slot < 0) continue;
#pragma unroll
            for (int nt = 0; nt < 4; ++nt) {
                float v1 = acc1[mt][nt][i];
                float v3 = acc3[mt][nt][i];
                float hv = v1 / (1.f + __expf(-v1)) * v3;
                int c = n0 + wc * 64 + nt * 16 + lrow;
                h[(size_t)slot * HID + c] = f2bf(hv);
            }
        }
    }
}

// ---------- GEMM2 (K-split x2): oslot_k[slot] = gate*(h[slot][khalf] @ w2[khalf]), bf16 out ----------
__global__ __launch_bounds__(256) void gemm2_kernel(const unsigned short* __restrict__ h,
                                                    const unsigned short* __restrict__ w2T,
                                                    unsigned short* __restrict__ oslot,
                                                    const int* __restrict__ counts,
                                                    const int* __restrict__ lists,
                                                    const float* __restrict__ gates) {
    int e = blockIdx.z;
    int cnt = counts[e];
    int rt = blockIdx.y;
    if (rt * 128 >= cnt) return;
    int bx = blockIdx.x;
    int ks = bx >> 3;                 // K-half 0/1
    int n0 = (bx & 7) * 128;
    int k0 = ks * (HID / 2);

    __shared__ unsigned short As[128 * 32];
    __shared__ unsigned short Bs[128 * 32];
    __shared__ int slotArr[128];

    int tid = threadIdx.x;
    if (tid < 128) {
        int r = rt * 128 + tid;
        slotArr[tid] = (r < cnt) ? lists[e * TLIST + r] : -1;
    }
    __syncthreads();

    int lane = tid & 63, wid = tid >> 6;
    int seg = lane >> 2, chunk = lane & 3;

    int rA0 = wid * 32 + seg, rA1 = wid * 32 + 16 + seg;
    int s0 = slotArr[rA0], s1 = slotArr[rA1];
    const unsigned short* gA0 = h + (size_t)(s0 < 0 ? 0 : s0) * HID + k0 + chunk * 8;
    const unsigned short* gA1 = h + (size_t)(s1 < 0 ? 0 : s1) * HID + k0 + chunk * 8;
    int rB0 = n0 + wid * 32 + seg, rB1 = rB0 + 16;
    const unsigned short* gB0 = w2T + ((size_t)e * EMB + rB0) * HID + k0 + chunk * 8;
    const unsigned short* gB1 = w2T + ((size_t)e * EMB + rB1) * HID + k0 + chunk * 8;
    unsigned short* lA0 = &As[wid * 1024];
    unsigned short* lA1 = &As[wid * 1024 + 512];
    unsigned short* lB0 = &Bs[wid * 1024];
    unsigned short* lB1 = &Bs[wid * 1024 + 512];

    int wr = wid >> 1, wc = wid & 1;
    int lrow = lane & 15, quad = lane >> 4;

    f32x4 zero4 = {0.f, 0.f, 0.f, 0.f};
    f32x4 acc[4][4];
#pragma unroll
    for (int mt = 0; mt < 4; ++mt)
#pragma unroll
        for (int nt = 0; nt < 4; ++nt) acc[mt][nt] = zero4;

    const int KT = (HID / 2) / 32;
    for (int kt = 0; kt < KT; ++kt) {
        ldst16(gA0, lA0); ldst16(gA1, lA1);
        ldst16(gB0, lB0); ldst16(gB1, lB1);
        gA0 += 32; gA1 += 32; gB0 += 32; gB1 += 32;
        __builtin_amdgcn_s_waitcnt(0);
        __syncthreads();
        short8 af[4], bf[4];
#pragma unroll
        for (int mt = 0; mt < 4; ++mt)
            af[mt] = *(const short8*)&As[(wr * 64 + mt * 16 + lrow) * 32 + quad * 8];
#pragma unroll
        for (int nt = 0; nt < 4; ++nt)
            bf[nt] = *(const short8*)&Bs[(wc * 64 + nt * 16 + lrow) * 32 + quad * 8];
#pragma unroll
        for (int mt = 0; mt < 4; ++mt)
#pragma unroll
            for (int nt = 0; nt < 4; ++nt)
                acc[mt][nt] = __builtin_amdgcn_mfma_f32_16x16x32_bf16(af[mt], bf[nt], acc[mt][nt], 0, 0, 0);
        __syncthreads();
    }

    unsigned short* ok = oslot + (size_t)ks * NSLOT * EMB;
#pragma unroll
    for (int mt = 0; mt < 4; ++mt) {
#pragma unroll
        for (int i = 0; i < 4; ++i) {
            int r = wr * 64 + mt * 16 + quad * 4 + i;
            int slot = slotArr[r];
            if (slot < 0) continue;
            float g = gates[slot];
#pragma unroll
            for (int nt = 0; nt < 4; ++nt) {
                int c = n0 + wc * 64 + nt * 16 + lrow;
                ok[(size_t)slot * EMB + c] = f2bf(g * acc[mt][nt][i]);
            }
        }
    }
}

// ---------- combine: y[t] = sum over 2 slots x 2 k-halves of bf16 partials ----------
__global__ __launch_bounds__(256) void combine_kernel(const unsigned short* __restrict__ oslot,
                                                      float* __restrict__ out) {
    int gid = blockIdx.x * 256 + threadIdx.x;     // over NTOK*EMB/8
    int t = gid / (EMB / 8);
    int r8 = (gid % (EMB / 8)) * 8;
    const unsigned short* p00 = oslot + (size_t)(2 * t) * EMB + r8;
    const unsigned short* p01 = oslot + (size_t)(2 * t + 1) * EMB + r8;
    const unsigned short* p10 = p00 + (size_t)NSLOT * EMB;
    const unsigned short* p11 = p01 + (size_t)NSLOT * EMB;
    short8 a = *(const short8*)p00, b = *(const short8*)p01;
    short8 c = *(const short8*)p10, d = *(const short8*)p11;
    float* o = out + (size_t)t * EMB + r8;
    float4 lo, hi;
#pragma unroll
    for (int j = 0; j < 4; ++j) {
        float v = bf2f((unsigned short)a[j]) + bf2f((unsigned short)b[j]) +
                  bf2f((unsigned short)c[j]) + bf2f((unsigned short)d[j]);
        ((float*)&lo)[j] = v;
    }
#pragma unroll
    for (int j = 4; j < 8; ++j) {
        float v = bf2f((unsigned short)a[j]) + bf2f((unsigned short)b[j]) +
                  bf2f((unsigned short)c[j]) + bf2f((unsigned short)d[j]);
        ((float*)&hi)[j - 4] = v;
    }
    *(float4*)o = lo;
    *(float4*)(o + 4) = hi;
}

extern "C" void kernel_launch(void* const* d_in, const int* in_sizes, int n_in,
                              void* d_out, int out_size, void* d_ws, size_t ws_size,
                              hipStream_t stream) {
    const float* x = (const float*)d_in[0];
    const float* wrout = (const float*)d_in[1];
    const float* w1 = (const float*)d_in[2];
    const float* w3 = (const float*)d_in[3];
    const float* w2 = (const float*)d_in[4];
    float* out = (float*)d_out;

    char* ws = (char*)d_ws;
    const size_t SW = (size_t)N_EXPERTS * EMB * HID * 2;
    const size_t SX = (size_t)NTOK * EMB * 2;
    const size_t SH = (size_t)NSLOT * HID * 2;
    const size_t SMETA = 256 + (size_t)N_EXPERTS * TLIST * 4 + (size_t)NSLOT * 4 + (size_t)NTOK * 4;
    const size_t NEEDED = 3 * SW + SX + SH + SMETA;
    if (ws_size < NEEDED) return;

    unsigned short* w1T = (unsigned short*)(ws);
    unsigned short* w3T = (unsigned short*)(ws + SW);
    unsigned short* w2T = (unsigned short*)(ws + 2 * SW);
    unsigned short* xbf = (unsigned short*)(ws + 3 * SW);
    unsigned short* hbuf = (unsigned short*)(ws + 3 * SW + SX);
    char* meta = ws + 3 * SW + SX + SH;
    int* counts = (int*)meta;
    int* lists = (int*)(meta + 256);
    float* gates = (float*)(meta + 256 + (size_t)N_EXPERTS * TLIST * 4);
    int* sel = (int*)(meta + 256 + (size_t)N_EXPERTS * TLIST * 4 + (size_t)NSLOT * 4);
    // oslot: 2 k-halves x NSLOT x EMB bf16 = 33.6 MB, overlays w1T (dead after gemm1)
    unsigned short* oslot = (unsigned short*)(ws);

    transpose_cvt<<<dim3(HID / 64, EMB / 64, N_EXPERTS), 256, 0, stream>>>(w1, w1T, EMB, HID);
    transpose_cvt<<<dim3(HID / 64, EMB / 64, N_EXPERTS), 256, 0, stream>>>(w3, w3T, EMB, HID);
    transpose_cvt<<<dim3(EMB / 64, HID / 64, N_EXPERTS), 256, 0, stream>>>(w2, w2T, HID, EMB);

    router_kernel<<<NTOK, 64, 0, stream>>>(x, wrout, xbf, sel, gates);
    build_lists<<<N_EXPERTS, 256, 0, stream>>>(sel, counts, lists);

    gemm1_kernel<<<dim3(HID / 128, NTOK / 128, N_EXPERTS), 256, 0, stream>>>(
        xbf, w1T, w3T, hbuf, counts, lists);
    gemm2_kernel<<<dim3(16, NTOK / 128, N_EXPERTS), 256, 0, stream>>>(
        hbuf, w2T, oslot, counts, lists, gates);
    combine_kernel<<<NTOK * EMB / 8 / 256, 256, 0, stream>>>(oslot, out);
}